// Round 6
// baseline (154.420 us; speedup 1.0000x reference)
//
#include <hip/hip_runtime.h>

typedef float f32x4 __attribute__((ext_vector_type(4)));
typedef __bf16 bf16x8 __attribute__((ext_vector_type(8)));

#define SPAT 65536   // t*h*w
#define CH   128
#define NE   8

// LDS layout (bytes):
//   ring slots 0..3 : 4 x 32KB at [0, 131072)  — bf16 weight images
//     prologue aliases: XS (X tile [256][128] bf16, swizzled) = slots 0-1;
//                       PL (gating partials f32[4][8][256])   = slot 2
//     slot 3 free at entry -> receives W1[0] DMA immediately.
//   misc at [131072, ...)
#define SLOT(i)  ((i) * 32768)
#define XS_OFF   0
#define PL_OFF   65536
#define SEL_OFF  131072   // 1024 : sel u32[256]
#define Q_OFF    132096   // 2048 : q f32[256][2]
#define CB_OFF   134144   // 4096 : combine bf16[256][8]
#define B1_OFF   138240   // 4096 : b1 f32[8][128] (natural order)
#define B2T_OFF  142336   // 2048 : b2^T bf16[128][8]
#define AL_OFF   144384   // 32   : alpha f32[8]
#define LDS_BYTES 144416

static __device__ __forceinline__ unsigned short f2b(float f) {
    unsigned u = __builtin_bit_cast(unsigned, f);
    unsigned r = u + 0x7FFFu + ((u >> 16) & 1u);
    return (unsigned short)(r >> 16);
}
static __device__ __forceinline__ unsigned pk2(float a, float b) {
    return (unsigned)f2b(a) | ((unsigned)f2b(b) << 16);
}

typedef const __attribute__((address_space(1))) void* as1cp;
typedef __attribute__((address_space(3))) void* as3p;
static __device__ __forceinline__ void gload16(const void* g, void* l) {
    __builtin_amdgcn_global_load_lds((as1cp)g, (as3p)l, 16, 0, 0);
}

// Pre-convert W1/W2 fp32 -> bf16 images (swizzled LDS byte order).
// W1 rows are PERMUTED so that GEMM1's D-fragment layout coincides with
// GEMM2's A-fragment layout (h1 stays in registers):
//   image row r holds W1 row o_real(r) = 32*(r>>5) + 8*((r>>2)&3) + 4*((r>>4)&1) + (r&3)
// W2 rows are natural.
__global__ void conv_w(const float* __restrict__ W1, const float* __restrict__ W2,
                       unsigned char* __restrict__ wimg) {
    const int gid = blockIdx.x * 256 + threadIdx.x;   // 32768 granules
    const int mat = gid >> 14;
    const int e   = (gid >> 11) & 7;
    const int o   = (gid >> 4) & 127;   // image row
    const int g   = gid & 15;
    int src_row = o;
    if (mat == 0)
        src_row = ((o >> 5) << 5) + (((o >> 2) & 3) << 3) + (((o >> 4) & 1) << 2) + (o & 3);
    const float* s = (mat ? W2 : W1) + (e * 16384 + src_row * 128 + g * 8);
    uint4 p;
    p.x = pk2(s[0], s[1]); p.y = pk2(s[2], s[3]);
    p.z = pk2(s[4], s[5]); p.w = pk2(s[6], s[7]);
    *(uint4*)(wimg + mat * 262144 + e * 32768 + o * 256 + ((g ^ (o & 7)) * 16)) = p;
}

// stage one 32KB weight image into an LDS slot (2 x gload16 per thread)
static __device__ __forceinline__ void stage_w(const unsigned char* __restrict__ src,
                                               unsigned char* dst, int t) {
    const int off = t * 16;
    gload16(src + off,         dst + off);
    gload16(src + 16384 + off, dst + 16384 + off);
}

__global__ __launch_bounds__(1024) __attribute__((amdgpu_waves_per_eu(4, 4)))
void moe_main(const float* __restrict__ x,  const float* __restrict__ gw,
              const float* __restrict__ gb, const float* __restrict__ b1,
              const float* __restrict__ alpha, const float* __restrict__ b2,
              const unsigned char* __restrict__ wimg, float* __restrict__ out)
{
    __shared__ __align__(16) unsigned char smem[LDS_BYTES];
    const int t = threadIdx.x, lane = t & 63, w = t >> 6, blk = blockIdx.x;
    const size_t xbase = (size_t)(blk >> 8) * (size_t)(CH * SPAT) + (size_t)((blk & 255) << 8);

    // W1[0] -> slot3 (free region): issue at entry, lands during prologue
    stage_w(wimg, smem + SLOT(3), t);

    // stage small params (disjoint misc regions)
    if (t < 256) ((f32x4*)(smem + B1_OFF))[t] = ((const f32x4*)b1)[t];
    else if (t >= 256 && t < 384) {
        const int j = t - 256;
        uint4 p;
        p.x = pk2(b2[0 * 128 + j], b2[1 * 128 + j]);
        p.y = pk2(b2[2 * 128 + j], b2[3 * 128 + j]);
        p.z = pk2(b2[4 * 128 + j], b2[5 * 128 + j]);
        p.w = pk2(b2[6 * 128 + j], b2[7 * 128 + j]);
        *(uint4*)(smem + B2T_OFF + j * 16) = p;
    } else if (t >= 384 && t < 392) {
        ((float*)(smem + AL_OFF))[t - 384] = alpha[t - 384];
    }

    // ---- stage X (fp32->bf16, swizzled, slots0-1) + gating partials (slot2) ----
    {
        const int m = t & 255, p = t >> 8;     // token, channel-part
        f32x4 plo = {0.f,0.f,0.f,0.f}, phi = {0.f,0.f,0.f,0.f};
        #pragma unroll
        for (int cc = 0; cc < 4; ++cc) {
            const int c0 = p * 32 + cc * 8;
            float v[8];
            #pragma unroll
            for (int j = 0; j < 8; ++j) v[j] = x[xbase + (size_t)(c0 + j) * SPAT + m];
            #pragma unroll
            for (int j = 0; j < 8; ++j) {
                const f32x4 g0 = *(const f32x4*)(gw + (c0 + j) * NE);
                const f32x4 g1 = *(const f32x4*)(gw + (c0 + j) * NE + 4);
                plo += v[j] * g0; phi += v[j] * g1;
            }
            uint4 pkv;
            pkv.x = pk2(v[0], v[1]); pkv.y = pk2(v[2], v[3]);
            pkv.z = pk2(v[4], v[5]); pkv.w = pk2(v[6], v[7]);
            const int g = p * 4 + cc;
            *(uint4*)(smem + XS_OFF + m * 256 + ((g ^ (m & 7)) * 16)) = pkv;
        }
        float* pl = (float*)(smem + PL_OFF);   // [part][e][tok], stride-1 tok
        #pragma unroll
        for (int e2 = 0; e2 < 4; ++e2) {
            pl[(p * 8 + e2)     * 256 + m] = plo[e2];
            pl[(p * 8 + 4 + e2) * 256 + m] = phi[e2];
        }
    }
    __syncthreads();   // S1
    if (t < 256) {
        const int m = t;
        const float* pl = (const float*)(smem + PL_OFF);
        float lg[8];
        #pragma unroll
        for (int e2 = 0; e2 < 8; ++e2) lg[e2] = gb[e2];
        #pragma unroll
        for (int pp = 0; pp < 4; ++pp)
            #pragma unroll
            for (int e2 = 0; e2 < 8; ++e2) lg[e2] += pl[(pp * 8 + e2) * 256 + m];
        int i0 = 0; float v0 = lg[0];
        #pragma unroll
        for (int e2 = 1; e2 < 8; ++e2) if (lg[e2] > v0) { v0 = lg[e2]; i0 = e2; }
        int i1 = -1; float v1 = -3.4e38f;
        #pragma unroll
        for (int e2 = 0; e2 < 8; ++e2) if (e2 != i0 && lg[e2] > v1) { v1 = lg[e2]; i1 = e2; }
        const float d  = expf(v1 - v0);
        const float q0 = 1.f / (1.f + d);
        const float q1 = d   / (1.f + d);
        ((unsigned*)(smem + SEL_OFF))[m] = (unsigned)i0 | ((unsigned)i1 << 8);
        ((float*)(smem + Q_OFF))[m * 2]     = q0;
        ((float*)(smem + Q_OFF))[m * 2 + 1] = q1;
        float cb[8];
        #pragma unroll
        for (int e2 = 0; e2 < 8; ++e2) cb[e2] = (e2 == i0) ? q0 : ((e2 == i1) ? q1 : 0.f);
        uint4 cw;
        cw.x = pk2(cb[0], cb[1]); cw.y = pk2(cb[2], cb[3]);
        cw.z = pk2(cb[4], cb[5]); cw.w = pk2(cb[6], cb[7]);
        *(uint4*)(smem + CB_OFF + m * 16) = cw;
    }
    __syncthreads();   // S2: SEL/Q/CB visible; PL dead (slot2 still DMA-free until S3)

    // per-lane token (row of GEMM2 A-frags): tokA = w*16 + (lane&15)
    const int col = lane & 15, kq = lane >> 4;
    const int tokA = w * 16 + col;
    const unsigned selu = ((const unsigned*)(smem + SEL_OFF))[tokA];
    const float cq0 = ((const float*)(smem + Q_OFF))[tokA * 2];
    const float cq1 = ((const float*)(smem + Q_OFF))[tokA * 2 + 1];

    // preload X B-frags (immutable): wave's 16 tokens, full K=128
    uint4 xb[4];
    #pragma unroll
    for (int kt = 0; kt < 4; ++kt)
        xb[kt] = *(const uint4*)(smem + XS_OFF + tokA * 256 + (((kt * 4 + kq) ^ (tokA & 7)) * 16));
    __syncthreads();   // S3: XS/PL dead -> all 4 slots DMA-targetable; W1[0] drained

    // fill the ring: W2[0]->slot0, W1[1]->slot1, W2[1]->slot2
    stage_w(wimg + 262144,         smem + SLOT(0), t);
    stage_w(wimg + 32768,          smem + SLOT(1), t);
    stage_w(wimg + 262144 + 32768, smem + SLOT(2), t);

    f32x4 acc[8] = {};   // [n2]: acc[tok=kq*4+i][o2=n2*16+col]

    #pragma unroll 1
    for (int e = 0; e < NE; ++e) {
        // WA slot: e even->3, odd->1 ; WB slot: e even->0, odd->2
        const unsigned waOff = 0x18000u ^ ((unsigned)(e & 1) << 16);
        const unsigned wbOff = ((unsigned)(e & 1) << 16);
        const unsigned char* WA = smem + waOff;
        const unsigned char* WB = smem + wbOff;
        const float alph = ((const float*)(smem + AL_OFF))[e];
        const float ce = ((selu & 255u) == (unsigned)e) ? cq0
                       : ((((selu >> 8) & 255u) == (unsigned)e) ? cq1 : 0.f);

        // ---- GEMM1: h1[all 128 o][wave's 16 tok] -> registers (pa) ----
        uint4 pa[4];
        #pragma unroll
        for (int ml = 0; ml < 8; ++ml) {
            const int o = ml * 16 + col;
            uint4 a1[4];
            #pragma unroll
            for (int kt = 0; kt < 4; ++kt)
                a1[kt] = *(const uint4*)(WA + o * 256 + (((kt * 4 + kq) ^ (o & 7)) * 16));
            f32x4 h = {0.f, 0.f, 0.f, 0.f};
            #pragma unroll
            for (int kt = 0; kt < 4; ++kt)
                h = __builtin_amdgcn_mfma_f32_16x16x32_bf16(
                        __builtin_bit_cast(bf16x8, a1[kt]),
                        __builtin_bit_cast(bf16x8, xb[kt]), h, 0, 0, 0);
            // image row permutation makes this tile's real o = ob + i
            const int ob = ((ml >> 1) << 5) + (kq << 3) + ((ml & 1) << 2);
            const f32x4 b1v = *(const f32x4*)(smem + B1_OFF + e * 512 + ob * 4);
            float hv[4];
            #pragma unroll
            for (int i = 0; i < 4; ++i) {
                float z = h[i] + b1v[i];
                z = (z > 0.f) ? z : alph * z;
                hv[i] = z * ce;
            }
            ((unsigned*)&pa[ml >> 1])[(ml & 1) * 2]     = pk2(hv[0], hv[1]);
            ((unsigned*)&pa[ml >> 1])[(ml & 1) * 2 + 1] = pk2(hv[2], hv[3]);
        }
        __syncthreads();                    // end phase 2e: WA slot free
        if (e < 6) stage_w(wimg + (e + 2) * 32768, smem + waOff, t);   // W1[e+2]

        // ---- GEMM2: acc[tok][o2] += h1^T(registers) . W2^T ----
        #pragma unroll
        for (int kt = 0; kt < 4; ++kt) {
            #pragma unroll
            for (int n2 = 0; n2 < 8; ++n2) {
                const int o2 = n2 * 16 + col;
                const uint4 wf = *(const uint4*)(WB + o2 * 256 + (((kt * 4 + kq) ^ (o2 & 7)) * 16));
                acc[n2] = __builtin_amdgcn_mfma_f32_16x16x32_bf16(
                        __builtin_bit_cast(bf16x8, pa[kt]),
                        __builtin_bit_cast(bf16x8, wf), acc[n2], 0, 0, 0);
            }
        }
        __syncthreads();                    // end phase 2e+1: WB slot free
        if (e < 6) stage_w(wimg + 262144 + (e + 2) * 32768, smem + wbOff, t);  // W2[e+2]
    }

    // ---- bias-combine as one K=32 MFMA per tile: acc += combine . b2 ----
    {
        const uint4 z4 = {0u, 0u, 0u, 0u};
        const uint4 paf = (kq == 0) ? *(const uint4*)(smem + CB_OFF + tokA * 16) : z4;
        #pragma unroll
        for (int n2 = 0; n2 < 8; ++n2) {
            const uint4 pbf = (kq == 0) ? *(const uint4*)(smem + B2T_OFF + (n2 * 16 + col) * 16) : z4;
            acc[n2] = __builtin_amdgcn_mfma_f32_16x16x32_bf16(
                    __builtin_bit_cast(bf16x8, paf),
                    __builtin_bit_cast(bf16x8, pbf), acc[n2], 0, 0, 0);
        }
    }

    // ---- epilogue: residual + coalesced dwordx4 ----
    const int tok0 = w * 16 + kq * 4;
    #pragma unroll
    for (int n2 = 0; n2 < 8; ++n2) {
        const int o2 = n2 * 16 + col;
        const size_t a = xbase + (size_t)o2 * SPAT + tok0;
        const f32x4 xv = *(const f32x4*)(x + a);
        f32x4 r = acc[n2];
        r += xv;
        *(f32x4*)(out + a) = r;
    }
}

extern "C" void kernel_launch(void* const* d_in, const int* in_sizes, int n_in,
                              void* d_out, int out_size, void* d_ws, size_t ws_size,
                              hipStream_t stream) {
    const float* x  = (const float*)d_in[0];
    const float* gw = (const float*)d_in[1];
    const float* gb = (const float*)d_in[2];
    const float* W1 = (const float*)d_in[3];
    const float* b1 = (const float*)d_in[4];
    const float* al = (const float*)d_in[5];
    const float* W2 = (const float*)d_in[6];
    const float* b2 = (const float*)d_in[7];
    (void)in_sizes; (void)n_in; (void)out_size; (void)ws_size;
    unsigned char* wimg = (unsigned char*)d_ws;   // needs 512 KiB
    float* out = (float*)d_out;

    conv_w<<<dim3(128), dim3(256), 0, stream>>>(W1, W2, wimg);
    moe_main<<<dim3(512), dim3(1024), 0, stream>>>(x, gw, gb, b1, al, b2, wimg, out);
}

// Round 7
// 148.914 us; speedup vs baseline: 1.0370x; 1.0370x over previous
//
#include <hip/hip_runtime.h>

typedef float f32x4  __attribute__((ext_vector_type(4)));
typedef float f32x16 __attribute__((ext_vector_type(16)));
typedef __bf16 bf16x8 __attribute__((ext_vector_type(8)));

#define SPAT 65536   // t*h*w
#define CH   128
#define NE   8

// LDS layout (bytes)
#define SLOTA   0        // 32768: W1[e] bf16 image (fixed slot)
#define SLOTB   32768    // 32768: W2[e] bf16 image (fixed slot)
#define GW_OFF  65536    // 4096 : gate_w f32[128][8]
#define B1_OFF  69632    // 4096 : b1 f32[8][128]
#define B2T_OFF 73728    // 4096 : b2^T bf16[128][16] (e 8..15 zero)
#define AL_OFF  77824    // 32   : alpha f32[8]
#define LDS_BYTES 77856

static __device__ __forceinline__ unsigned short f2b(float f) {
    unsigned u = __builtin_bit_cast(unsigned, f);
    unsigned r = u + 0x7FFFu + ((u >> 16) & 1u);
    return (unsigned short)(r >> 16);
}
static __device__ __forceinline__ unsigned pk2(float a, float b) {
    return (unsigned)f2b(a) | ((unsigned)f2b(b) << 16);
}

typedef const __attribute__((address_space(1))) void* as1cp;
typedef __attribute__((address_space(3))) void* as3p;
static __device__ __forceinline__ void gload16(const void* g, void* l) {
    __builtin_amdgcn_global_load_lds((as1cp)g, (as3p)l, 16, 0, 0);
}

// Pre-convert W1/W2 fp32 -> bf16 images for 32x32x16 MFMA:
//  - 16B-granule XOR swizzle within each 256B row: stored[p] = src granule (p ^ (r&15))
//  - W1 rows PERMUTED so GEMM1's D-fragment == GEMM2's A-fragment:
//      image row r holds real W1 row P(r) = kt2*16 + hi*8 + half*4 + i
//      with n = 4*(r>>5) + ((r>>3)&3), kt2 = n>>1, half = n&1, hi = (r>>2)&1, i = r&3.
//  - W2 rows natural (rows = p, cols = o).
__global__ void conv_w(const float* __restrict__ W1, const float* __restrict__ W2,
                       unsigned char* __restrict__ wimg) {
    const int gid = blockIdx.x * 256 + threadIdx.x;   // 32768 granules
    const int mat = gid >> 14;
    const int e   = (gid >> 11) & 7;
    const int r   = (gid >> 4) & 127;
    const int p   = gid & 15;
    const int sg  = p ^ (r & 15);
    int src_row = r;
    if (mat == 0) {
        const int n = 4 * (r >> 5) + ((r >> 3) & 3);
        src_row = (n >> 1) * 16 + ((r >> 2) & 1) * 8 + (n & 1) * 4 + (r & 3);
    }
    const float* s = (mat ? W2 : W1) + (e * 16384 + src_row * 128 + sg * 8);
    uint4 pk;
    pk.x = pk2(s[0], s[1]); pk.y = pk2(s[2], s[3]);
    pk.z = pk2(s[4], s[5]); pk.w = pk2(s[6], s[7]);
    *(uint4*)(wimg + mat * 262144 + e * 32768 + r * 256 + p * 16) = pk;
}

// stage one 32KB weight image into an LDS slot (4 x gload16 per thread, 512 thr)
static __device__ __forceinline__ void stage_w(const unsigned char* __restrict__ src,
                                               unsigned char* dst, int t) {
    const int off = t * 16;
    gload16(src + off,          dst + off);
    gload16(src + 8192  + off,  dst + 8192  + off);
    gload16(src + 16384 + off,  dst + 16384 + off);
    gload16(src + 24576 + off,  dst + 24576 + off);
}

__global__ __launch_bounds__(512, 2)
void moe_main(const float* __restrict__ x,  const float* __restrict__ gw,
              const float* __restrict__ gb, const float* __restrict__ b1,
              const float* __restrict__ alpha, const float* __restrict__ b2,
              const unsigned char* __restrict__ wimg, float* __restrict__ out)
{
    __shared__ __align__(16) unsigned char smem[LDS_BYTES];
    const int t = threadIdx.x, lane = t & 63, w = t >> 6, blk = blockIdx.x;
    const int ltok = lane & 31, hi = lane >> 5, l15 = lane & 15;
    const size_t xbase = (size_t)(blk >> 8) * (size_t)(CH * SPAT) + (size_t)((blk & 255) << 8);
    const int m = w * 32 + ltok;            // this lane's block-local token

    // W1[0]->A, W2[0]->B: issue at entry (land by S1's drain)
    stage_w(wimg,          smem + SLOTA, t);
    stage_w(wimg + 262144, smem + SLOTB, t);

    // issue this lane's 64 fp32 x-loads (token m, channels kc*16 + hi*8 + j)
    float v[8][8];
    #pragma unroll
    for (int kc = 0; kc < 8; ++kc)
        #pragma unroll
        for (int j = 0; j < 8; ++j)
            v[kc][j] = x[xbase + (size_t)(kc * 16 + hi * 8 + j) * SPAT + m];

    // stage small params
    if (t < 256)      ((f32x4*)(smem + GW_OFF))[t]       = ((const f32x4*)gw)[t];
    else              ((f32x4*)(smem + B1_OFF))[t - 256] = ((const f32x4*)b1)[t - 256];
    if (t < 128) {
        uint4 pkv, z4 = {0u, 0u, 0u, 0u};
        pkv.x = pk2(b2[0 * 128 + t], b2[1 * 128 + t]);
        pkv.y = pk2(b2[2 * 128 + t], b2[3 * 128 + t]);
        pkv.z = pk2(b2[4 * 128 + t], b2[5 * 128 + t]);
        pkv.w = pk2(b2[6 * 128 + t], b2[7 * 128 + t]);
        *(uint4*)(smem + B2T_OFF + t * 32)      = pkv;
        *(uint4*)(smem + B2T_OFF + t * 32 + 16) = z4;
    } else if (t >= 128 && t < 136) {
        ((float*)(smem + AL_OFF))[t - 128] = alpha[t - 128];
    }
    __syncthreads();   // S1: gw/b1/b2T visible; W1[0],W2[0] landed; v loads drained

    // ---- fp32 gating (gw via LDS broadcast) + xb pack ----
    f32x4 plo = {0.f,0.f,0.f,0.f}, phi = {0.f,0.f,0.f,0.f};
    uint4 xb[8];
    #pragma unroll
    for (int kc = 0; kc < 8; ++kc) {
        const int c0 = kc * 16 + hi * 8;
        #pragma unroll
        for (int j = 0; j < 8; ++j) {
            const f32x4 g0 = *(const f32x4*)(smem + GW_OFF + (c0 + j) * 32);
            const f32x4 g1 = *(const f32x4*)(smem + GW_OFF + (c0 + j) * 32 + 16);
            plo += v[kc][j] * g0; phi += v[kc][j] * g1;
        }
        xb[kc].x = pk2(v[kc][0], v[kc][1]); xb[kc].y = pk2(v[kc][2], v[kc][3]);
        xb[kc].z = pk2(v[kc][4], v[kc][5]); xb[kc].w = pk2(v[kc][6], v[kc][7]);
    }
    #pragma unroll
    for (int i2 = 0; i2 < 4; ++i2) {
        plo[i2] += __shfl_xor(plo[i2], 32, 64);
        phi[i2] += __shfl_xor(phi[i2], 32, 64);
    }
    int i0, i1; float q0, q1; uint4 cbw;
    {
        float lg[8];
        #pragma unroll
        for (int e2 = 0; e2 < 4; ++e2) { lg[e2] = plo[e2] + gb[e2]; lg[4 + e2] = phi[e2] + gb[4 + e2]; }
        i0 = 0; float v0 = lg[0];
        #pragma unroll
        for (int e2 = 1; e2 < 8; ++e2) if (lg[e2] > v0) { v0 = lg[e2]; i0 = e2; }
        i1 = -1; float v1 = -3.4e38f;
        #pragma unroll
        for (int e2 = 0; e2 < 8; ++e2) if (e2 != i0 && lg[e2] > v1) { v1 = lg[e2]; i1 = e2; }
        const float d = expf(v1 - v0);
        q0 = 1.f / (1.f + d);
        q1 = d   / (1.f + d);
        float cb[8];
        #pragma unroll
        for (int e2 = 0; e2 < 8; ++e2) cb[e2] = (e2 == i0) ? q0 : ((e2 == i1) ? q1 : 0.f);
        cbw.x = pk2(cb[0], cb[1]); cbw.y = pk2(cb[2], cb[3]);
        cbw.z = pk2(cb[4], cb[5]); cbw.w = pk2(cb[6], cb[7]);
    }

    f32x16 acc[4] = {};   // acc[n2]: D[tok 32][p = n2*32 + ltok]

    #pragma unroll 1
    for (int e = 0; e < NE; ++e) {
        const float alph = ((const float*)(smem + AL_OFF))[e];
        const float ce = (i0 == e) ? q0 : ((i1 == e) ? q1 : 0.f);

        // ---- GEMM1: h1[all 128 o][this lane's token] -> pa registers ----
        uint4 pa[8];
        #pragma unroll 2
        for (int g = 0; g < 4; ++g) {
            uint4 a1[8];
            #pragma unroll
            for (int kc = 0; kc < 8; ++kc)
                a1[kc] = *(const uint4*)(smem + SLOTA + (g * 32 + ltok) * 256
                                          + (((kc * 2 + hi) ^ l15) * 16));
            f32x16 h = {};
            #pragma unroll
            for (int kc = 0; kc < 8; ++kc)
                h = __builtin_amdgcn_mfma_f32_32x32x16_bf16(
                        __builtin_bit_cast(bf16x8, a1[kc]),
                        __builtin_bit_cast(bf16x8, xb[kc]), h, 0, 0, 0);
            #pragma unroll
            for (int q = 0; q < 4; ++q) {
                const int n = 4 * g + q, kt2 = n >> 1, half = q & 1;
                const int obase = kt2 * 16 + hi * 8 + half * 4;
                const f32x4 b1v = *(const f32x4*)(smem + B1_OFF + e * 512 + obase * 4);
                float hv[4];
                #pragma unroll
                for (int i = 0; i < 4; ++i) {
                    float z = h[q * 4 + i] + b1v[i];
                    z = (z > 0.f) ? z : alph * z;
                    hv[i] = z * ce;
                }
                ((unsigned*)&pa[kt2])[half * 2]     = pk2(hv[0], hv[1]);
                ((unsigned*)&pa[kt2])[half * 2 + 1] = pk2(hv[2], hv[3]);
            }
        }
        __syncthreads();   // B1: SLOTA free
        if (e < 7) stage_w(wimg + (e + 1) * 32768, smem + SLOTA, t);   // W1[e+1], lands by B2

        // ---- GEMM2: acc[tok][p] += h1(regs) . W2^T ----
        #pragma unroll
        for (int kt2 = 0; kt2 < 8; ++kt2) {
            uint4 wf[4];
            #pragma unroll
            for (int n2 = 0; n2 < 4; ++n2)
                wf[n2] = *(const uint4*)(smem + SLOTB + (n2 * 32 + ltok) * 256
                                          + (((kt2 * 2 + hi) ^ l15) * 16));
            #pragma unroll
            for (int n2 = 0; n2 < 4; ++n2)
                acc[n2] = __builtin_amdgcn_mfma_f32_32x32x16_bf16(
                        __builtin_bit_cast(bf16x8, pa[kt2]),
                        __builtin_bit_cast(bf16x8, wf[n2]), acc[n2], 0, 0, 0);
        }
        if (e < 7) {
            __syncthreads();   // B2: SLOTB free; W1[e+1] will drain at next barrier
            stage_w(wimg + 262144 + (e + 1) * 32768, smem + SLOTB, t); // W2[e+1], lands by B1(e+1)
        }
    }

    // ---- bias-combine as one K=16 MFMA per p-group: acc += combine . b2 ----
    {
        const uint4 z4 = {0u, 0u, 0u, 0u};
        const uint4 aop = hi ? z4 : cbw;
        #pragma unroll
        for (int n2 = 0; n2 < 4; ++n2) {
            const uint4 bop = *(const uint4*)(smem + B2T_OFF + (n2 * 32 + ltok) * 32 + hi * 16);
            acc[n2] = __builtin_amdgcn_mfma_f32_32x32x16_bf16(
                    __builtin_bit_cast(bf16x8, aop),
                    __builtin_bit_cast(bf16x8, bop), acc[n2], 0, 0, 0);
        }
    }

    // ---- epilogue: residual + f32x4 stores (D rows = tok = w*32 + 8q + 4hi + i) ----
    #pragma unroll
    for (int n2 = 0; n2 < 4; ++n2) {
        const int p = n2 * 32 + ltok;
        #pragma unroll
        for (int q = 0; q < 4; ++q) {
            const int tok0 = w * 32 + q * 8 + hi * 4;
            const size_t a = xbase + (size_t)p * SPAT + tok0;
            const f32x4 xv = *(const f32x4*)(x + a);
            f32x4 r;
            #pragma unroll
            for (int i = 0; i < 4; ++i) r[i] = acc[n2][q * 4 + i] + xv[i];
            *(f32x4*)(out + a) = r;
        }
    }
}

extern "C" void kernel_launch(void* const* d_in, const int* in_sizes, int n_in,
                              void* d_out, int out_size, void* d_ws, size_t ws_size,
                              hipStream_t stream) {
    const float* x  = (const float*)d_in[0];
    const float* gw = (const float*)d_in[1];
    const float* gb = (const float*)d_in[2];
    const float* W1 = (const float*)d_in[3];
    const float* b1 = (const float*)d_in[4];
    const float* al = (const float*)d_in[5];
    const float* W2 = (const float*)d_in[6];
    const float* b2 = (const float*)d_in[7];
    (void)in_sizes; (void)n_in; (void)out_size; (void)ws_size;
    unsigned char* wimg = (unsigned char*)d_ws;   // needs 512 KiB
    float* out = (float*)d_out;

    conv_w<<<dim3(128), dim3(256), 0, stream>>>(W1, W2, wimg);
    moe_main<<<dim3(512), dim3(512), 0, stream>>>(x, gw, gb, b1, al, b2, wimg, out);
}

// Round 8
// 121.044 us; speedup vs baseline: 1.2757x; 1.2303x over previous
//
#include <hip/hip_runtime.h>

typedef float f32x4  __attribute__((ext_vector_type(4)));
typedef float f32x16 __attribute__((ext_vector_type(16)));
typedef __bf16 bf16x8 __attribute__((ext_vector_type(8)));

#define SPAT 65536   // t*h*w
#define CH   128
#define NE   8

// LDS layout (bytes): 4 x 32KB weight ring + params
#define SLOT(i)  ((i) * 32768)
#define B1_OFF   131072   // 4096 : b1 f32[8][128]
#define B2T_OFF  135168   // 4096 : b2^T bf16[128][16] (e 8..15 zero)
#define AL_OFF   139264   // 32   : alpha f32[8]
#define LDS_BYTES 139296

static __device__ __forceinline__ unsigned short f2b(float f) {
    unsigned u = __builtin_bit_cast(unsigned, f);
    unsigned r = u + 0x7FFFu + ((u >> 16) & 1u);
    return (unsigned short)(r >> 16);
}
static __device__ __forceinline__ unsigned pk2(float a, float b) {
    return (unsigned)f2b(a) | ((unsigned)f2b(b) << 16);
}

typedef const __attribute__((address_space(1))) void* as1cp;
typedef __attribute__((address_space(3))) void* as3p;
static __device__ __forceinline__ void gload16(const void* g, void* l) {
    __builtin_amdgcn_global_load_lds((as1cp)g, (as3p)l, 16, 0, 0);
}

// Pre-convert W1/W2 fp32 -> bf16 images for 32x32x16 MFMA (verified in R7):
//  - 16B-granule XOR swizzle within each 256B row: stored[p] = src granule (p ^ (r&15))
//  - W1 rows PERMUTED so GEMM1's D-fragment == GEMM2's A-fragment:
//      image row r holds real W1 row P(r): n = 4*(r>>5) + ((r>>3)&3),
//      P(r) = (n>>1)*16 + ((r>>2)&1)*8 + (n&1)*4 + (r&3).
//  - W2 rows natural.
__global__ void conv_w(const float* __restrict__ W1, const float* __restrict__ W2,
                       unsigned char* __restrict__ wimg) {
    const int gid = blockIdx.x * 256 + threadIdx.x;   // 32768 granules
    const int mat = gid >> 14;
    const int e   = (gid >> 11) & 7;
    const int r   = (gid >> 4) & 127;
    const int p   = gid & 15;
    const int sg  = p ^ (r & 15);
    int src_row = r;
    if (mat == 0) {
        const int n = 4 * (r >> 5) + ((r >> 3) & 3);
        src_row = (n >> 1) * 16 + ((r >> 2) & 1) * 8 + (n & 1) * 4 + (r & 3);
    }
    const float* s = (mat ? W2 : W1) + (e * 16384 + src_row * 128 + sg * 8);
    uint4 pk;
    pk.x = pk2(s[0], s[1]); pk.y = pk2(s[2], s[3]);
    pk.z = pk2(s[4], s[5]); pk.w = pk2(s[6], s[7]);
    *(uint4*)(wimg + mat * 262144 + e * 32768 + r * 256 + p * 16) = pk;
}

// stage one 32KB weight image into an LDS slot (4 x gload16 per thread, 512 thr)
static __device__ __forceinline__ void stage_w(const unsigned char* __restrict__ src,
                                               unsigned char* dst, int t) {
    const int off = t * 16;
    gload16(src + off,          dst + off);
    gload16(src + 8192  + off,  dst + 8192  + off);
    gload16(src + 16384 + off,  dst + 16384 + off);
    gload16(src + 24576 + off,  dst + 24576 + off);
}

// Occupancy: pin 2 waves/EU (1 block/CU at 512 thr) -> 256-reg budget, so the
// ~170-reg working set fits WITHOUT scratch spill (R7: allocator chased
// occupancy, kept 92 VGPRs, spilled ~500B/thread -> +130MB HBM writes).
__global__ __launch_bounds__(512) __attribute__((amdgpu_waves_per_eu(2, 2)))
void moe_main(const float* __restrict__ x,  const float* __restrict__ gw,
              const float* __restrict__ gb, const float* __restrict__ b1,
              const float* __restrict__ alpha, const float* __restrict__ b2,
              const unsigned char* __restrict__ wimg, float* __restrict__ out)
{
    __shared__ __align__(16) unsigned char smem[LDS_BYTES];
    const int t = threadIdx.x, lane = t & 63, w = t >> 6, blk = blockIdx.x;
    const int ltok = lane & 31, hi = lane >> 5, l15 = lane & 15;
    const size_t xbase = (size_t)(blk >> 8) * (size_t)(CH * SPAT) + (size_t)((blk & 255) << 8);
    const int m = w * 32 + ltok;            // this lane's block-local token

    // W1[0]->slot0, W2[0]->slot1: issue at entry, land by S1
    stage_w(wimg,          smem + SLOT(0), t);
    stage_w(wimg + 262144, smem + SLOT(1), t);

    // stage small params
    if (t < 256) ((f32x4*)(smem + B1_OFF))[t] = ((const f32x4*)b1)[t];
    if (t < 128) {
        uint4 pkv, z4 = {0u, 0u, 0u, 0u};
        pkv.x = pk2(b2[0 * 128 + t], b2[1 * 128 + t]);
        pkv.y = pk2(b2[2 * 128 + t], b2[3 * 128 + t]);
        pkv.z = pk2(b2[4 * 128 + t], b2[5 * 128 + t]);
        pkv.w = pk2(b2[6 * 128 + t], b2[7 * 128 + t]);
        *(uint4*)(smem + B2T_OFF + t * 32)      = pkv;
        *(uint4*)(smem + B2T_OFF + t * 32 + 16) = z4;
    } else if (t >= 128 && t < 136) {
        ((float*)(smem + AL_OFF))[t - 128] = alpha[t - 128];
    }

    // ---- per-kc: load x(8ch), fp32 gating partials (gw from global/L2), pack xb ----
    f32x4 plo = {0.f,0.f,0.f,0.f}, phi = {0.f,0.f,0.f,0.f};
    uint4 xb[8];
    #pragma unroll
    for (int kc = 0; kc < 8; ++kc) {
        const int c0 = kc * 16 + hi * 8;
        float v8[8];
        #pragma unroll
        for (int j = 0; j < 8; ++j) v8[j] = x[xbase + (size_t)(c0 + j) * SPAT + m];
        #pragma unroll
        for (int j = 0; j < 8; ++j) {
            const f32x4 g0 = *(const f32x4*)(gw + (c0 + j) * NE);
            const f32x4 g1 = *(const f32x4*)(gw + (c0 + j) * NE + 4);
            plo += v8[j] * g0; phi += v8[j] * g1;
        }
        xb[kc].x = pk2(v8[0], v8[1]); xb[kc].y = pk2(v8[2], v8[3]);
        xb[kc].z = pk2(v8[4], v8[5]); xb[kc].w = pk2(v8[6], v8[7]);
    }
    #pragma unroll
    for (int i2 = 0; i2 < 4; ++i2) {
        plo[i2] += __shfl_xor(plo[i2], 32, 64);
        phi[i2] += __shfl_xor(phi[i2], 32, 64);
    }
    int i0, i1; float q0, q1; uint4 cbw;
    {
        float lg[8];
        #pragma unroll
        for (int e2 = 0; e2 < 4; ++e2) { lg[e2] = plo[e2] + gb[e2]; lg[4 + e2] = phi[e2] + gb[4 + e2]; }
        i0 = 0; float v0 = lg[0];
        #pragma unroll
        for (int e2 = 1; e2 < 8; ++e2) if (lg[e2] > v0) { v0 = lg[e2]; i0 = e2; }
        i1 = -1; float v1 = -3.4e38f;
        #pragma unroll
        for (int e2 = 0; e2 < 8; ++e2) if (e2 != i0 && lg[e2] > v1) { v1 = lg[e2]; i1 = e2; }
        const float d = expf(v1 - v0);
        q0 = 1.f / (1.f + d);
        q1 = d   / (1.f + d);
        float cb[8];
        #pragma unroll
        for (int e2 = 0; e2 < 8; ++e2) cb[e2] = (e2 == i0) ? q0 : ((e2 == i1) ? q1 : 0.f);
        cbw.x = pk2(cb[0], cb[1]); cbw.y = pk2(cb[2], cb[3]);
        cbw.z = pk2(cb[4], cb[5]); cbw.w = pk2(cb[6], cb[7]);
    }
    __syncthreads();   // S1: W1[0]/W2[0] landed; b1/b2T/alpha visible

    f32x16 acc[4] = {};   // acc[n2]: D[tok 32][p = n2*32 + ltok]

    #pragma unroll 1
    for (int e = 0; e < NE; ++e) {
        const int cur = (e & 1) << 1;   // slots: even e -> 0,1 ; odd e -> 2,3
        if (e < 7) {                    // prefetch next pair into the other slots
            stage_w(wimg + (e + 1) * 32768,          smem + SLOT(cur ^ 2), t);
            stage_w(wimg + 262144 + (e + 1) * 32768, smem + SLOT((cur ^ 2) + 1), t);
        }
        const unsigned char* WA = smem + SLOT(cur);
        const unsigned char* WB = smem + SLOT(cur) + 32768;
        const float alph = ((const float*)(smem + AL_OFF))[e];
        const float ce = (i0 == e) ? q0 : ((i1 == e) ? q1 : 0.f);

        // fused per-32-row group: GEMM1 group -> pa(8 regs) -> its 2 GEMM2 K-steps
        #pragma unroll 1
        for (int g = 0; g < 4; ++g) {
            uint4 a1[8];
            #pragma unroll
            for (int kc = 0; kc < 8; ++kc)
                a1[kc] = *(const uint4*)(WA + (g * 32 + ltok) * 256
                                          + (((kc * 2 + hi) ^ l15) * 16));
            f32x16 h = {};
            #pragma unroll
            for (int kc = 0; kc < 8; ++kc)
                h = __builtin_amdgcn_mfma_f32_32x32x16_bf16(
                        __builtin_bit_cast(bf16x8, a1[kc]),
                        __builtin_bit_cast(bf16x8, xb[kc]), h, 0, 0, 0);
            uint4 pa2[2];
            #pragma unroll
            for (int q = 0; q < 4; ++q) {
                const int n = 4 * g + q, kt2 = n >> 1, half = n & 1;
                const int obase = kt2 * 16 + hi * 8 + half * 4;
                const f32x4 b1v = *(const f32x4*)(smem + B1_OFF + e * 512 + obase * 4);
                float hv[4];
                #pragma unroll
                for (int i = 0; i < 4; ++i) {
                    float z = h[q * 4 + i] + b1v[i];
                    z = (z > 0.f) ? z : alph * z;
                    hv[i] = z * ce;
                }
                ((unsigned*)&pa2[q >> 1])[half * 2]     = pk2(hv[0], hv[1]);
                ((unsigned*)&pa2[q >> 1])[half * 2 + 1] = pk2(hv[2], hv[3]);
            }
            #pragma unroll
            for (int dk = 0; dk < 2; ++dk) {
                const int kt2 = 2 * g + dk;
                #pragma unroll
                for (int n2 = 0; n2 < 4; ++n2) {
                    const uint4 wf = *(const uint4*)(WB + (n2 * 32 + ltok) * 256
                                          + (((kt2 * 2 + hi) ^ l15) * 16));
                    acc[n2] = __builtin_amdgcn_mfma_f32_32x32x16_bf16(
                            __builtin_bit_cast(bf16x8, pa2[dk]),
                            __builtin_bit_cast(bf16x8, wf), acc[n2], 0, 0, 0);
                }
            }
        }
        __syncthreads();   // phase end: prefetch drained; cur slots free next iter
    }

    // ---- bias-combine as one K=16 MFMA per p-group: acc += combine . b2 ----
    {
        const uint4 z4 = {0u, 0u, 0u, 0u};
        const uint4 aop = hi ? z4 : cbw;
        #pragma unroll
        for (int n2 = 0; n2 < 4; ++n2) {
            const uint4 bop = *(const uint4*)(smem + B2T_OFF + (n2 * 32 + ltok) * 32 + hi * 16);
            acc[n2] = __builtin_amdgcn_mfma_f32_32x32x16_bf16(
                    __builtin_bit_cast(bf16x8, aop),
                    __builtin_bit_cast(bf16x8, bop), acc[n2], 0, 0, 0);
        }
    }

    // ---- epilogue: residual + f32x4 stores (D rows: tok = w*32 + 8q + 4hi + i) ----
    #pragma unroll
    for (int n2 = 0; n2 < 4; ++n2) {
        const int p = n2 * 32 + ltok;
        #pragma unroll
        for (int q = 0; q < 4; ++q) {
            const int tok0 = w * 32 + q * 8 + hi * 4;
            const size_t a = xbase + (size_t)p * SPAT + tok0;
            const f32x4 xv = *(const f32x4*)(x + a);
            f32x4 r;
            #pragma unroll
            for (int i = 0; i < 4; ++i) r[i] = acc[n2][q * 4 + i] + xv[i];
            *(f32x4*)(out + a) = r;
        }
    }
}

extern "C" void kernel_launch(void* const* d_in, const int* in_sizes, int n_in,
                              void* d_out, int out_size, void* d_ws, size_t ws_size,
                              hipStream_t stream) {
    const float* x  = (const float*)d_in[0];
    const float* gw = (const float*)d_in[1];
    const float* gb = (const float*)d_in[2];
    const float* W1 = (const float*)d_in[3];
    const float* b1 = (const float*)d_in[4];
    const float* al = (const float*)d_in[5];
    const float* W2 = (const float*)d_in[6];
    const float* b2 = (const float*)d_in[7];
    (void)in_sizes; (void)n_in; (void)out_size; (void)ws_size;
    unsigned char* wimg = (unsigned char*)d_ws;   // needs 512 KiB
    float* out = (float*)d_out;

    conv_w<<<dim3(128), dim3(256), 0, stream>>>(W1, W2, wimg);
    moe_main<<<dim3(512), dim3(512), 0, stream>>>(x, gw, gb, b1, al, b2, wimg, out);
}